// Round 7
// baseline (144.101 us; speedup 1.0000x reference)
//
#include <hip/hip_runtime.h>

// IGANN: per-feature 2-layer MLPs (1->16->16->1), summed over 256 features + linear term.
// R7: register-resident weights. R6 was latency-bound on per-feature weight loads
//     (VALUBusy 33%, MfmaUtil 6%, VGPR 36 — compiler didn't hoist; 5 dependent L2 loads
//     per feature iter). Now FCHUNK=8 (32 groups, grid 4096): all 8 features' weights
//     preloaded into ~64 VGPRs before the row loop -> inner loop has ZERO global loads.
//     launch_bounds(256,4): cap 128 for est ~111 live VGPRs (don't squeeze -> R3/R4 spills).
//     Accepted cost: 32-B x row-slices -> ~2x x over-fetch, 2x atomics (HBM only 13% busy).

typedef float    f32x4 __attribute__((ext_vector_type(4)));
typedef _Float16 f16x4 __attribute__((ext_vector_type(4)));
typedef __fp16   pk16x2 __attribute__((ext_vector_type(2)));

__device__ __forceinline__ f16x4 cvt4(f32x4 v) {
    pk16x2 lo = __builtin_amdgcn_cvt_pkrtz(v[0], v[1]);
    pk16x2 hi = __builtin_amdgcn_cvt_pkrtz(v[2], v[3]);
    union { unsigned u[2]; f16x4 h; } un;
    un.u[0] = __builtin_bit_cast(unsigned, lo);
    un.u[1] = __builtin_bit_cast(unsigned, hi);
    return un.h;
}

__device__ __forceinline__ f16x4 splat_h(float s) {
    pk16x2 p = __builtin_amdgcn_cvt_pkrtz(s, s);
    unsigned u = __builtin_bit_cast(unsigned, p);
    union { unsigned u[2]; f16x4 h; } un;
    un.u[0] = u; un.u[1] = u;
    return un.h;
}

__device__ __forceinline__ f16x4 relu_h(f16x4 v) {
    f16x4 z = {};
    return __builtin_elementwise_max(v, z);
}

__device__ __forceinline__ f32x4 relu_f(f32x4 v) {
    f32x4 z = {0.f, 0.f, 0.f, 0.f};
    return __builtin_elementwise_max(v, z);
}

#define FCHUNK 8    // features per block (32 groups of 8 = 256)
#define LDSR   10   // padded LDS row stride in floats (10r mod 32 distinct -> <=2-way, free)

__global__ __launch_bounds__(256, 4) void igann_kernel(
    const float* __restrict__ x,  const float* __restrict__ la,
    const float* __restrict__ bb, const float* __restrict__ W1,
    const float* __restrict__ b1, const float* __restrict__ W2,
    const float* __restrict__ b2, const float* __restrict__ W3,
    const float* __restrict__ b3, float* __restrict__ out)
{
    const int tid = threadIdx.x;
    const int l   = tid & 63;     // lane
    const int w   = tid >> 6;     // wave in block (0..3)
    const int r   = l & 15;       // MFMA row m (A) / col n (D)
    const int g   = l >> 4;       // k-group
    const int g4  = g * 4;
    const int r16 = r * 16;

    const int rb = blockIdx.x >> 5;    // row block (0..127), 256 rows each
    const int fg = blockIdx.x & 31;    // feature group (0..31)
    const int f0 = fg * FCHUNK;
    const int rowbase = rb * 256;

    __shared__ float ldsx[256 * LDSR];   // 10 KB: x slice [row][col(8)+pad]
    __shared__ float red[256];           // per-row subnet partial sums

    // ---- preload ALL weights for this feature group into registers ----
    f16x4 w1h[FCHUNK], b1h[FCHUNK], bfr[FCHUNK];
    float b2k[FCHUNK], w3k[FCHUNK];
    #pragma unroll
    for (int u = 0; u < FCHUNK; ++u) {
        const int f = f0 + u;
        w1h[u] = cvt4(*(const f32x4*)(W1 + f * 16 + g4));
        b1h[u] = cvt4(*(const f32x4*)(b1 + f * 16 + g4));
        bfr[u] = cvt4(*(const f32x4*)(W2 + (size_t)f * 256 + r16 + g4));
        b2k[u] = b2[f * 16 + r];
        w3k[u] = W3[f * 16 + r];
    }

    // ---- stage x slice (2 lanes cover one 32-B row-slice) ----
    {
        const int rr = tid >> 1;          // 0..127
        const int c4 = (tid & 1) * 4;     // 0,4
        #pragma unroll
        for (int it = 0; it < 2; ++it) {
            const int row = it * 128 + rr;
            f32x4 v = *(const f32x4*)(x + (size_t)(rowbase + row) * 256 + f0 + c4);
            *(f32x4*)(ldsx + row * LDSR + c4) = v;
        }
    }
    __syncthreads();

    const float* xw = ldsx + (w * 64 + r) * LDSR;

    f32x4 acc[4];     // [tile][j]: D row g4+j (batch row within tile), col r (channel)
    #pragma unroll
    for (int t = 0; t < 4; ++t) acc[t] = (f32x4){0.f, 0.f, 0.f, 0.f};

    #pragma unroll
    for (int fi = 0; fi < FCHUNK; fi += 4) {
        f32x4 xv[4];
        #pragma unroll
        for (int t = 0; t < 4; ++t)
            xv[t] = *(const f32x4*)(xw + t * 16 * LDSR + fi);

        #pragma unroll
        for (int u = 0; u < 4; ++u) {
            const int f = fi + u;            // weight-array index (compile-time)
            const f32x4 cinit = {b2k[f], b2k[f], b2k[f], b2k[f]};
            const f32x4 w3k4  = {w3k[f], w3k[f], w3k[f], w3k[f]};
            #pragma unroll
            for (int t = 0; t < 4; ++t) {
                f16x4 xs4 = splat_h(xv[t][u]);
                f16x4 h = relu_h(xs4 * w1h[f] + b1h[f]);  // v_pk_fma_f16 + v_pk_max_f16
                f32x4 d = __builtin_amdgcn_mfma_f32_16x16x16f16(h, bfr[f], cinit, 0, 0, 0);
                acc[t] += relu_f(d) * w3k4;
            }
        }
    }

    // reduce over the 16 output channels (lane bits 0..3); r==0 lanes hold row sums
    #pragma unroll
    for (int t = 0; t < 4; ++t)
        #pragma unroll
        for (int j = 0; j < 4; ++j) {
            float v = acc[t][j];
            v += __shfl_xor(v, 1, 64);
            v += __shfl_xor(v, 2, 64);
            v += __shfl_xor(v, 4, 64);
            v += __shfl_xor(v, 8, 64);
            if (r == 0) red[w * 64 + t * 16 + g4 + j] = v;
        }
    __syncthreads();

    // ---- epilogue: thread tid owns local row tid ----
    float lin = 0.f, b3s = 0.f;
    const float* xrow = ldsx + tid * LDSR;
    #pragma unroll
    for (int c = 0; c < FCHUNK; ++c) {
        lin = fmaf(xrow[c], la[f0 + c], lin);
        b3s += b3[f0 + c];
    }
    const float v = red[tid] + lin + b3s + (fg == 0 ? bb[0] : 0.f);
    atomicAdd(out + rowbase + tid, v);
}

extern "C" void kernel_launch(void* const* d_in, const int* in_sizes, int n_in,
                              void* d_out, int out_size, void* d_ws, size_t ws_size,
                              hipStream_t stream) {
    const float* x  = (const float*)d_in[0];
    const float* la = (const float*)d_in[1];
    const float* bb = (const float*)d_in[2];
    const float* W1 = (const float*)d_in[3];
    const float* b1 = (const float*)d_in[4];
    const float* W2 = (const float*)d_in[5];
    const float* b2 = (const float*)d_in[6];
    const float* W3 = (const float*)d_in[7];
    const float* b3 = (const float*)d_in[8];
    float* out = (float*)d_out;

    (void)hipMemsetAsync(out, 0, (size_t)out_size * sizeof(float), stream);

    dim3 grid(4096), block(256);
    hipLaunchKernelGGL(igann_kernel, grid, block, 0, stream,
                       x, la, bb, W1, b1, W2, b2, W3, b3, out);
}